// Round 16
// baseline (976.874 us; speedup 1.0000x reference)
//
#include <hip/hip_runtime.h>
#include <hip/hip_fp8.h>

#define N_ROWS 4096
#define H_DIM  1024
#define V_SIZE 32000

typedef int   i32x4 __attribute__((ext_vector_type(4)));
typedef int   i32x8 __attribute__((ext_vector_type(8)));
typedef float f32x4 __attribute__((ext_vector_type(4)));

typedef __attribute__((address_space(1))) void* gas_ptr;
typedef __attribute__((address_space(3))) void* las_ptr;

__global__ void zero_f32(float* __restrict__ p, int n) {
  int i = blockIdx.x * blockDim.x + threadIdx.x;
  if (i < n) p[i] = 0.0f;
}

__device__ __forceinline__ unsigned pk4_fp8(float a, float b, float c, float d) {
#if __has_builtin(__builtin_amdgcn_cvt_pk_fp8_f32)
  int v = __builtin_amdgcn_cvt_pk_fp8_f32(a, b, 0, false);
  v = __builtin_amdgcn_cvt_pk_fp8_f32(c, d, v, true);
  return (unsigned)v;
#else
  __hip_fp8_e4m3 qa(a), qb(b), qc(c), qd(d);
  return (unsigned)qa.__x | ((unsigned)qb.__x << 8) | ((unsigned)qc.__x << 16) |
         ((unsigned)qd.__x << 24);
#endif
}

// W path (Ws/Wt): fp32 -> fp8 e4m3, XOR swizzle pre-baked per 128B block
// (r9-verified 0-conflict; valid for any BK since it permutes 16B units
// WITHIN each 128B block): out[row*1024 + (k ^ ((row&7)<<4))] = fp8(in).
__global__ void cvt_fp8(const float* __restrict__ in, unsigned char* __restrict__ out, int total16) {
  int idx = blockIdx.x * blockDim.x + threadIdx.x;
  int stride = gridDim.x * blockDim.x;
  for (; idx < total16; idx += stride) {
    unsigned row = (unsigned)idx >> 6;
    unsigned k0 = ((unsigned)idx & 63u) << 4;
    const float4* p = (const float4*)(in + (size_t)row * H_DIM + k0);
    float4 f0 = p[0], f1 = p[1], f2 = p[2], f3 = p[3];
    unsigned long long u0 = (unsigned long long)pk4_fp8(f0.x, f0.y, f0.z, f0.w) |
                            ((unsigned long long)pk4_fp8(f1.x, f1.y, f1.z, f1.w) << 32);
    unsigned long long u1 = (unsigned long long)pk4_fp8(f2.x, f2.y, f2.z, f2.w) |
                            ((unsigned long long)pk4_fp8(f3.x, f3.y, f3.z, f3.w) << 32);
    unsigned key = (row & 7u) << 4;
    unsigned char* ob = out + (size_t)row * H_DIM;
    *(unsigned long long*)(ob + (k0 ^ key)) = u0;
    *(unsigned long long*)(ob + ((k0 ^ key) + 8u)) = u1;
  }
}

// A path (x/tx): fp32 -> fp8 FRAGMENT-LINEAR (r12/r13-verified): fragment
// (rg, kt128, kk2) is one coalesced global_load_dwordx4 at
// rg*16384 + kt*2048 + kk2*1024 + lane*16.
__global__ void cvt_fragA(const float* __restrict__ in, unsigned char* __restrict__ out, int total16) {
  int idx = blockIdx.x * blockDim.x + threadIdx.x;
  int stride = gridDim.x * blockDim.x;
  for (; idx < total16; idx += stride) {
    unsigned row = (unsigned)idx >> 6;
    unsigned u16 = (unsigned)idx & 63u;
    const float4* p = (const float4*)(in + (size_t)row * H_DIM + u16 * 16u);
    float4 f0 = p[0], f1 = p[1], f2 = p[2], f3 = p[3];
    uint4 o;
    o.x = pk4_fp8(f0.x, f0.y, f0.z, f0.w);
    o.y = pk4_fp8(f1.x, f1.y, f1.z, f1.w);
    o.z = pk4_fp8(f2.x, f2.y, f2.z, f2.w);
    o.w = pk4_fp8(f3.x, f3.y, f3.z, f3.w);
    unsigned rg = row >> 4, c = row & 15u, kt = u16 >> 3, u = u16 & 7u;
    *(uint4*)(out + rg * 16384u + kt * 2048u + u * 256u + c * 16u) = o;
  }
}

__device__ __forceinline__ i32x8 cat8(i32x4 a, i32x4 b) {
  return __builtin_shufflevector(a, b, 0, 1, 2, 3, 4, 5, 6, 7);
}

// MX-scaled fp8 MFMA, unit scales (E8M0 127 = x1.0). Validated r8/r9.
__device__ __forceinline__ f32x4 mx_mfma(i32x8 a, i32x8 b, f32x4 c) {
  return __builtin_amdgcn_mfma_scale_f32_16x16x128_f8f6f4(
      a, b, c, 0 /*A=fp8*/, 0 /*B=fp8*/, 0, 0x7f7f7f7f, 0, 0x7f7f7f7f);
}

// Fused dual-GEMM (MX-fp8 16x16x128) + KL partial sums.
// BM=128 x BN=128, BK=256 (2x r9 -> per-step overhead amortized over 2x MFMA;
// 125 block-steps/CU instead of 250). 4 waves (2x2 of 64x64 dual), 2 blocks/CU.
// A from L2 (fragment-linear). LDS = W only, single-buffered:
// Ws [128 cols][256B] @0, Wt @32768 (64KB total). r9 bulk-sync loop shape.
// B ds_read stream: r9's exact 0-conflict phase pattern per 128B block
// (reads at h2*128 + ((kk2*64|g*16)^key)); 256B-row stage is linear from the
// pre-baked source. Per row n: Zt=sum exp(t), U=sum exp(t)(t-s), Zs=sum exp(s).
__global__ __launch_bounds__(256, 2) void fused_kl(
    const unsigned char* __restrict__ xF, const unsigned char* __restrict__ txF,
    const unsigned char* __restrict__ ws8, const unsigned char* __restrict__ wt8,
    float* __restrict__ Zt, float* __restrict__ Uu, float* __restrict__ Zs) {
  __shared__ __align__(16) char smem[65536];  // Ws@0 (32KB) | Wt@32768 (32KB)

  const unsigned tid = threadIdx.x;
  const unsigned lane = tid & 63u;
  const unsigned w = tid >> 6;
  const unsigned wr = w >> 1, wc = w & 1u;

  const unsigned b = blockIdx.x;
  const unsigned rb = (b & 7u) * 4u + ((b >> 3) & 3u);  // row-block 0..31
  const unsigned chunk = b >> 5;                        // vocab chunk 0..15
  const unsigned row0 = rb * 128u;
  const unsigned t_begin = chunk * 15u + (chunk < 10u ? chunk : 10u);
  const unsigned t_count = (chunk < 10u) ? 16u : 15u;

  const unsigned c = lane & 15u;
  const unsigned g = (lane >> 4) & 3u;
  const unsigned key = (c & 7u) << 4;
  const unsigned f0 = (g << 4) ^ key;
  const unsigned f1 = (64u | (g << 4)) ^ key;

  // B ds_read bases: col*(256B row) + in-block offset; ni via +4096 imm,
  // K-half via +128 imm, teacher tile via +32768 imm.
  const char* pB0 = smem + (wc * 64u + c) * 256u + f0;
  const char* pB1 = smem + (wc * 64u + c) * 256u + f1;

  // A fragment-linear base: rg0 = rb*8 + wr*4 (BM=128).
  const unsigned aoff0 = (rb * 8u + wr * 4u) * 16384u + lane * 16u;

  // W staging: wave w stages 16KB: w0/w1 -> Ws rows 0-63/64-127, w2/w3 -> Wt.
  // Lane covers row (i*4 + lane>>4), byte (lane&15)*16 of the 256B k-chunk.
  const unsigned char* gW = (w < 2u) ? ws8 : wt8;
  char* sdst = smem + w * 16384u + lane * 16u;
  const unsigned srow = (w & 1u) * 64u + (lane >> 4);
  const unsigned sb = (lane & 15u) * 16u;

  float zt1 = 0.f, uu1 = 0.f, zs1 = 0.f;
  const f32x4 fzero = {0.f, 0.f, 0.f, 0.f};

  for (unsigned vt = 0; vt < t_count; ++vt) {
    const unsigned v0 = (t_begin + vt) * 128u;
    const unsigned char* sv = gW + (size_t)(v0 + srow) * H_DIM + sb;

    f32x4 acc_s[4][4], acc_t[4][4];
#pragma unroll
    for (int mi = 0; mi < 4; ++mi)
#pragma unroll
      for (int ni = 0; ni < 4; ++ni) { acc_s[mi][ni] = fzero; acc_t[mi][ni] = fzero; }

    for (unsigned kt4 = 0; kt4 < 4; ++kt4) {   // BK=256 steps
      __syncthreads();  // previous step's ds_reads done before overwrite
      {
        const unsigned char* sk = sv + kt4 * 256u;
#pragma unroll
        for (unsigned i = 0; i < 16; ++i)
          __builtin_amdgcn_global_load_lds((gas_ptr)(sk + (size_t)i * (4u * H_DIM)),
                                           (las_ptr)(sdst + i * 1024u), 16, 0, 0);
      }
      __syncthreads();  // staging visible

#pragma unroll
      for (unsigned h2 = 0; h2 < 2; ++h2) {    // two K=128 halves
        const unsigned ktA = kt4 * 2u + h2;
        const int ho = (int)(h2 * 128u);
        // ---- student: A from L2, B from Ws LDS ----
        {
          i32x4 a0[4], a1[4];
#pragma unroll
          for (int mi = 0; mi < 4; ++mi) {
            const unsigned char* pa = xF + aoff0 + (unsigned)mi * 16384u + ktA * 2048u;
            a0[mi] = *(const i32x4*)pa;
            a1[mi] = *(const i32x4*)(pa + 1024);
          }
          __builtin_amdgcn_s_setprio(1);
#pragma unroll
          for (int ni = 0; ni < 4; ++ni) {
            i32x8 bs = cat8(*(const i32x4*)(pB0 + ni * 4096 + ho),
                            *(const i32x4*)(pB1 + ni * 4096 + ho));
#pragma unroll
            for (int mi = 0; mi < 4; ++mi)
              acc_s[mi][ni] = mx_mfma(cat8(a0[mi], a1[mi]), bs, acc_s[mi][ni]);
          }
          __builtin_amdgcn_s_setprio(0);
        }
        // ---- teacher: A from L2, B from Wt LDS (+32768 imm) ----
        {
          i32x4 a0[4], a1[4];
#pragma unroll
          for (int mi = 0; mi < 4; ++mi) {
            const unsigned char* pa = txF + aoff0 + (unsigned)mi * 16384u + ktA * 2048u;
            a0[mi] = *(const i32x4*)pa;
            a1[mi] = *(const i32x4*)(pa + 1024);
          }
          __builtin_amdgcn_s_setprio(1);
#pragma unroll
          for (int ni = 0; ni < 4; ++ni) {
            i32x8 bt = cat8(*(const i32x4*)(pB0 + ni * 4096 + ho + 32768),
                            *(const i32x4*)(pB1 + ni * 4096 + ho + 32768));
#pragma unroll
            for (int mi = 0; mi < 4; ++mi)
              acc_t[mi][ni] = mx_mfma(cat8(a0[mi], a1[mi]), bt, acc_t[mi][ni]);
          }
          __builtin_amdgcn_s_setprio(0);
        }
      }
    }

    // Epilogue: fold this 128-col logit tile into per-lane KL sums.
    // C/D layout: col = lane&15, row = (lane>>4)*4 + j (m89-verified)
#pragma unroll
    for (int mi = 0; mi < 4; ++mi)
#pragma unroll
      for (int j = 0; j < 4; ++j) {
        float ztl = 0.f, uul = 0.f, zsl = 0.f;
#pragma unroll
        for (int ni = 0; ni < 4; ++ni) {
          float s = acc_s[mi][ni][j];
          float tt = acc_t[mi][ni][j];
          float et = __expf(tt);
          ztl += et;
          uul += et * (tt - s);
          zsl += __expf(s);
        }
        ztl += __shfl_xor(ztl, 1); ztl += __shfl_xor(ztl, 2);
        ztl += __shfl_xor(ztl, 4); ztl += __shfl_xor(ztl, 8);
        uul += __shfl_xor(uul, 1); uul += __shfl_xor(uul, 2);
        uul += __shfl_xor(uul, 4); uul += __shfl_xor(uul, 8);
        zsl += __shfl_xor(zsl, 1); zsl += __shfl_xor(zsl, 2);
        zsl += __shfl_xor(zsl, 4); zsl += __shfl_xor(zsl, 8);
        if (c == (unsigned)(mi * 4 + j)) { zt1 += ztl; uu1 += uul; zs1 += zsl; }
      }
  }

  // Lane (g,c) owns row: wr*64 + (c>>2)*16 + g*4 + (c&3)  (bijective over 64 rows)
  {
    unsigned n = row0 + wr * 64u + (c >> 2) * 16u + g * 4u + (c & 3u);
    atomicAdd(&Zt[n], zt1);
    atomicAdd(&Uu[n], uu1);
    atomicAdd(&Zs[n], zs1);
  }
}

// KL_n = U/Zt - log Zt + log Zs ; out = mean over N, float32.
__global__ void finalize_kl(const float* __restrict__ Zt, const float* __restrict__ Uu,
                            const float* __restrict__ Zs, float* __restrict__ out) {
  __shared__ float red[4];
  float s = 0.f;
  for (int r = threadIdx.x; r < N_ROWS; r += 256) {
    s += Uu[r] / Zt[r] - __logf(Zt[r]) + __logf(Zs[r]);
  }
  s += __shfl_xor(s, 1); s += __shfl_xor(s, 2); s += __shfl_xor(s, 4);
  s += __shfl_xor(s, 8); s += __shfl_xor(s, 16); s += __shfl_xor(s, 32);
  if ((threadIdx.x & 63) == 0) red[threadIdx.x >> 6] = s;
  __syncthreads();
  if (threadIdx.x == 0) {
    float tot = red[0] + red[1] + red[2] + red[3];
    out[0] = tot / (float)N_ROWS;
  }
}

extern "C" void kernel_launch(void* const* d_in, const int* in_sizes, int n_in,
                              void* d_out, int out_size, void* d_ws, size_t ws_size,
                              hipStream_t stream) {
  const float* x  = (const float*)d_in[0];
  const float* tx = (const float*)d_in[1];
  const float* Ws = (const float*)d_in[2];
  const float* Wt = (const float*)d_in[3];

  char* ws = (char*)d_ws;
  float* Zt = (float*)ws;
  float* Uu = Zt + N_ROWS;
  float* Zs = Uu + N_ROWS;
  unsigned char* xF  = (unsigned char*)(ws + 65536);
  unsigned char* txF = xF  + (size_t)N_ROWS * H_DIM;
  unsigned char* ws8 = txF + (size_t)N_ROWS * H_DIM;
  unsigned char* wt8 = ws8 + (size_t)V_SIZE * H_DIM;

  zero_f32<<<(3 * N_ROWS) / 256, 256, 0, stream>>>(Zt, 3 * N_ROWS);
  cvt_fragA<<<1024, 256, 0, stream>>>(x,  xF,  N_ROWS * (H_DIM / 16));
  cvt_fragA<<<1024, 256, 0, stream>>>(tx, txF, N_ROWS * (H_DIM / 16));
  cvt_fp8<<<2048, 256, 0, stream>>>(Ws, ws8, V_SIZE * (H_DIM / 16));
  cvt_fp8<<<2048, 256, 0, stream>>>(Wt, wt8, V_SIZE * (H_DIM / 16));
  fused_kl<<<512, 256, 0, stream>>>(xF, txF, ws8, wt8, Zt, Uu, Zs);
  finalize_kl<<<1, 256, 0, stream>>>(Zt, Uu, Zs, (float*)d_out);
}

// Round 17
// 408.620 us; speedup vs baseline: 2.3907x; 2.3907x over previous
//
#include <hip/hip_runtime.h>
#include <hip/hip_fp8.h>

#define N_ROWS 4096
#define H_DIM  1024
#define V_SIZE 32000

typedef int   i32x4 __attribute__((ext_vector_type(4)));
typedef int   i32x8 __attribute__((ext_vector_type(8)));
typedef float f32x4 __attribute__((ext_vector_type(4)));

typedef __attribute__((address_space(1))) void* gas_ptr;
typedef __attribute__((address_space(3))) void* las_ptr;

__device__ __forceinline__ unsigned pk4_fp8(float a, float b, float c, float d) {
#if __has_builtin(__builtin_amdgcn_cvt_pk_fp8_f32)
  int v = __builtin_amdgcn_cvt_pk_fp8_f32(a, b, 0, false);
  v = __builtin_amdgcn_cvt_pk_fp8_f32(c, d, v, true);
  return (unsigned)v;
#else
  __hip_fp8_e4m3 qa(a), qb(b), qc(c), qd(d);
  return (unsigned)qa.__x | ((unsigned)qb.__x << 8) | ((unsigned)qc.__x << 16) |
         ((unsigned)qd.__x << 24);
#endif
}

// One kernel: zero the 12288-float accumulator region + convert all four
// fp32 arrays to fp8 e4m3 with the r9-verified LDS swizzle PRE-BAKED:
// out[row*1024 + (k ^ ((row&7)<<4))] = fp8(in[row*1024 + k]).
// Segments (16-elem chunks): [0,768) zero | x | tx | Ws | Wt.
__global__ void cvt_all(const float* __restrict__ x, const float* __restrict__ tx,
                        const float* __restrict__ Ws, const float* __restrict__ Wt,
                        unsigned char* __restrict__ x8, unsigned char* __restrict__ tx8,
                        unsigned char* __restrict__ ws8, unsigned char* __restrict__ wt8,
                        float* __restrict__ Z) {
  const long NZ = 768;                      // 12288 floats / 16
  const long NX = (long)N_ROWS * (H_DIM / 16);
  const long NW = (long)V_SIZE * (H_DIM / 16);
  const long total = NZ + 2 * NX + 2 * NW;
  const long stride = (long)gridDim.x * blockDim.x;
  for (long idx = (long)blockIdx.x * blockDim.x + threadIdx.x; idx < total; idx += stride) {
    if (idx < NZ) {
      float4 z4 = {0.f, 0.f, 0.f, 0.f};
      float4* p = (float4*)(Z + idx * 16);
      p[0] = z4; p[1] = z4; p[2] = z4; p[3] = z4;
      continue;
    }
    long r = idx - NZ;
    const float* in;
    unsigned char* out;
    if (r < NX)            { in = x;  out = x8; }
    else if (r < 2 * NX)   { in = tx; out = tx8; r -= NX; }
    else if (r < 2 * NX + NW) { in = Ws; out = ws8; r -= 2 * NX; }
    else                   { in = Wt; out = wt8; r -= 2 * NX + NW; }
    unsigned row = (unsigned)(r >> 6);
    unsigned k0 = ((unsigned)r & 63u) << 4;
    const float4* p = (const float4*)(in + (size_t)row * H_DIM + k0);
    float4 f0 = p[0], f1 = p[1], f2 = p[2], f3 = p[3];
    unsigned long long u0 = (unsigned long long)pk4_fp8(f0.x, f0.y, f0.z, f0.w) |
                            ((unsigned long long)pk4_fp8(f1.x, f1.y, f1.z, f1.w) << 32);
    unsigned long long u1 = (unsigned long long)pk4_fp8(f2.x, f2.y, f2.z, f2.w) |
                            ((unsigned long long)pk4_fp8(f3.x, f3.y, f3.z, f3.w) << 32);
    unsigned key = (row & 7u) << 4;
    unsigned char* ob = out + (size_t)row * H_DIM;
    *(unsigned long long*)(ob + (k0 ^ key)) = u0;
    *(unsigned long long*)(ob + ((k0 ^ key) + 8u)) = u1;
  }
}

__device__ __forceinline__ i32x8 cat8(i32x4 a, i32x4 b) {
  return __builtin_shufflevector(a, b, 0, 1, 2, 3, 4, 5, 6, 7);
}

// MX-scaled fp8 MFMA, unit scales (E8M0 127 = x1.0): numerically identical to
// plain e4m3 matmul at the 4661 TF MX rate. Validated r8/r9.
__device__ __forceinline__ f32x4 mx_mfma(i32x8 a, i32x8 b, f32x4 c) {
  return __builtin_amdgcn_mfma_scale_f32_16x16x128_f8f6f4(
      a, b, c, 0 /*A=fp8*/, 0 /*B=fp8*/, 0, 0x7f7f7f7f, 0, 0x7f7f7f7f);
}

// ============ fused_kl: byte-for-byte the round-9 kernel ============
// (session best: 385 us dispatch, MfmaUtil 31%, 0 bank conflicts, VGPR 124,
// no spill). Bulk-sync BK=128 dual-GEMM; all four tiles via LDS; ds_read
// stream HW-verified conflict-free; MX-fp8 16x16x128 with unit scales.
__global__ __launch_bounds__(256, 2) void fused_kl(
    const unsigned char* __restrict__ x8, const unsigned char* __restrict__ tx8,
    const unsigned char* __restrict__ ws8, const unsigned char* __restrict__ wt8,
    float* __restrict__ Zt, float* __restrict__ Uu, float* __restrict__ Zs) {
  __shared__ __align__(16) char smem[65536];  // x | tx (+16KB) | Ws (+32KB) | Wt (+48KB)

  const unsigned tid = threadIdx.x;
  const unsigned lane = tid & 63u;
  const unsigned w = tid >> 6;
  const unsigned wr = w >> 1, wc = w & 1;

  const unsigned b = blockIdx.x;
  const unsigned rb = (b & 7u) * 4u + ((b >> 3) & 3u);  // row-block 0..31
  const unsigned chunk = b >> 5;                        // vocab chunk 0..15
  const unsigned row0 = rb * 128u;
  const unsigned t_begin = chunk * 15u + (chunk < 10u ? chunk : 10u);
  const unsigned t_count = (chunk < 10u) ? 16u : 15u;

  const unsigned c = lane & 15u;        // fragment row/col index
  const unsigned g = (lane >> 4) & 3u;  // K-group
  const unsigned key = (c & 7u) << 4;   // swizzle key (bits 4-6)

  // Loop-invariant base pointers; other addressing via ds offset immediates:
  // + mi*2048 (16 rows x 128B), +16384 for teacher tile.
  const char* pA[2];
  const char* pB[2];
#pragma unroll
  for (int kk2 = 0; kk2 < 2; ++kk2) {
    unsigned f = (((unsigned)kk2 << 6) | (g << 4)) ^ key;
    pA[kk2] = smem + (wr * 64u + c) * 128u + f;
    pB[kk2] = smem + 32768u + (wc * 64u + c) * 128u + f;
  }

  // Staging: wave w stages its own 16KB tile (pre-swizzled source, linear LDS).
  char* sdst = smem + w * 16384u + lane * 16u;
  const unsigned char* gsrc = (w == 0) ? x8 : (w == 1) ? tx8 : (w == 2) ? ws8 : wt8;
  const bool a_wave = (w < 2);
  const unsigned srow = lane >> 3;
  const unsigned sb = (lane & 7u) * 16u;

  float zt1 = 0.f, uu1 = 0.f, zs1 = 0.f;
  const f32x4 fzero = {0.f, 0.f, 0.f, 0.f};

  for (unsigned vt = 0; vt < t_count; ++vt) {
    const unsigned tile_row0 = a_wave ? row0 : (t_begin + vt) * 128u;
    const unsigned char* sv = gsrc + (size_t)(tile_row0 + srow) * H_DIM + sb;

    f32x4 acc_s[4][4], acc_t[4][4];
#pragma unroll
    for (int mi = 0; mi < 4; ++mi)
#pragma unroll
      for (int ni = 0; ni < 4; ++ni) { acc_s[mi][ni] = fzero; acc_t[mi][ni] = fzero; }

    for (unsigned kt = 0; kt < 8; ++kt) {
      __syncthreads();  // previous step's ds_reads done before overwrite
      {
        const unsigned char* sk = sv + kt * 128u;
#pragma unroll
        for (unsigned i = 0; i < 16; ++i)
          __builtin_amdgcn_global_load_lds((gas_ptr)(sk + (size_t)i * (8u * H_DIM)),
                                           (las_ptr)(sdst + i * 1024u), 16, 0, 0);
      }
      __syncthreads();  // drains vmcnt(0) -> staging visible to all waves

      // ---- student pass (x, Ws) ----
      {
        i32x8 ax[4];
#pragma unroll
        for (int mi = 0; mi < 4; ++mi)
          ax[mi] = cat8(*(const i32x4*)(pA[0] + mi * 2048),
                        *(const i32x4*)(pA[1] + mi * 2048));
#pragma unroll
        for (int ni = 0; ni < 4; ++ni) {
          i32x8 bs = cat8(*(const i32x4*)(pB[0] + ni * 2048),
                          *(const i32x4*)(pB[1] + ni * 2048));
#pragma unroll
          for (int mi = 0; mi < 4; ++mi)
            acc_s[mi][ni] = mx_mfma(ax[mi], bs, acc_s[mi][ni]);
        }
      }
      // ---- teacher pass (tx, Wt) via +16384 ds offset immediates ----
      {
        i32x8 at[4];
#pragma unroll
        for (int mi = 0; mi < 4; ++mi)
          at[mi] = cat8(*(const i32x4*)(pA[0] + mi * 2048 + 16384),
                        *(const i32x4*)(pA[1] + mi * 2048 + 16384));
#pragma unroll
        for (int ni = 0; ni < 4; ++ni) {
          i32x8 bt = cat8(*(const i32x4*)(pB[0] + ni * 2048 + 16384),
                          *(const i32x4*)(pB[1] + ni * 2048 + 16384));
#pragma unroll
          for (int mi = 0; mi < 4; ++mi)
            acc_t[mi][ni] = mx_mfma(at[mi], bt, acc_t[mi][ni]);
        }
      }
    }

    // Epilogue: fold this 128-col logit tile into per-lane KL sums.
    // C/D layout: col = lane&15, row = (lane>>4)*4 + j (m89-verified)
#pragma unroll
    for (int mi = 0; mi < 4; ++mi)
#pragma unroll
      for (int j = 0; j < 4; ++j) {
        float ztl = 0.f, uul = 0.f, zsl = 0.f;
#pragma unroll
        for (int ni = 0; ni < 4; ++ni) {
          float s = acc_s[mi][ni][j];
          float tt = acc_t[mi][ni][j];
          float et = __expf(tt);
          ztl += et;
          uul += et * (tt - s);
          zsl += __expf(s);
        }
        ztl += __shfl_xor(ztl, 1); ztl += __shfl_xor(ztl, 2);
        ztl += __shfl_xor(ztl, 4); ztl += __shfl_xor(ztl, 8);
        uul += __shfl_xor(uul, 1); uul += __shfl_xor(uul, 2);
        uul += __shfl_xor(uul, 4); uul += __shfl_xor(uul, 8);
        zsl += __shfl_xor(zsl, 1); zsl += __shfl_xor(zsl, 2);
        zsl += __shfl_xor(zsl, 4); zsl += __shfl_xor(zsl, 8);
        if (c == (unsigned)(mi * 4 + j)) { zt1 += ztl; uu1 += uul; zs1 += zsl; }
      }
  }

  // Lane (g,c) owns row: wr*64 + (c>>2)*16 + g*4 + (c&3)  (bijective over 64 rows)
  {
    unsigned n = row0 + wr * 64u + (c >> 2) * 16u + g * 4u + (c & 3u);
    atomicAdd(&Zt[n], zt1);
    atomicAdd(&Uu[n], uu1);
    atomicAdd(&Zs[n], zs1);
  }
}

// KL_n = U/Zt - log Zt + log Zs ; out = mean over N, float32.
__global__ void finalize_kl(const float* __restrict__ Zt, const float* __restrict__ Uu,
                            const float* __restrict__ Zs, float* __restrict__ out) {
  __shared__ float red[4];
  float s = 0.f;
  for (int r = threadIdx.x; r < N_ROWS; r += 256) {
    s += Uu[r] / Zt[r] - __logf(Zt[r]) + __logf(Zs[r]);
  }
  s += __shfl_xor(s, 1); s += __shfl_xor(s, 2); s += __shfl_xor(s, 4);
  s += __shfl_xor(s, 8); s += __shfl_xor(s, 16); s += __shfl_xor(s, 32);
  if ((threadIdx.x & 63) == 0) red[threadIdx.x >> 6] = s;
  __syncthreads();
  if (threadIdx.x == 0) {
    float tot = red[0] + red[1] + red[2] + red[3];
    out[0] = tot / (float)N_ROWS;
  }
}

extern "C" void kernel_launch(void* const* d_in, const int* in_sizes, int n_in,
                              void* d_out, int out_size, void* d_ws, size_t ws_size,
                              hipStream_t stream) {
  const float* x  = (const float*)d_in[0];
  const float* tx = (const float*)d_in[1];
  const float* Ws = (const float*)d_in[2];
  const float* Wt = (const float*)d_in[3];

  char* ws = (char*)d_ws;
  float* Zt = (float*)ws;
  float* Uu = Zt + N_ROWS;
  float* Zs = Uu + N_ROWS;
  unsigned char* x8  = (unsigned char*)(ws + 65536);
  unsigned char* tx8 = x8  + (size_t)N_ROWS * H_DIM;
  unsigned char* ws8 = tx8 + (size_t)N_ROWS * H_DIM;
  unsigned char* wt8 = ws8 + (size_t)V_SIZE * H_DIM;

  cvt_all<<<4096, 256, 0, stream>>>(x, tx, Ws, Wt, x8, tx8, ws8, wt8, Zt);
  fused_kl<<<512, 256, 0, stream>>>(x8, tx8, ws8, wt8, Zt, Uu, Zs);
  finalize_kl<<<1, 256, 0, stream>>>(Zt, Uu, Zs, (float*)d_out);
}